// Round 2
// baseline (697.753 us; speedup 1.0000x reference)
//
#include <hip/hip_runtime.h>

#define B_ 4
#define N_ 4096
#define C_ 256
#define M_ 2048

typedef __attribute__((ext_vector_type(8))) short short8;
typedef __attribute__((ext_vector_type(4))) short short4v;
typedef __attribute__((ext_vector_type(4))) float f32x4;

union U16x8 { uint4 u4; unsigned short us[8]; short8 s8; };
union U16x4 { uint2 u2; unsigned short us[4]; short4v s4; };

__device__ __forceinline__ float bf2f(unsigned short h) {
    unsigned int u = ((unsigned int)h) << 16;
    return __builtin_bit_cast(float, u);
}
__device__ __forceinline__ unsigned short f2bf(float f) {
    unsigned int u = __builtin_bit_cast(unsigned int, f);
    u += 0x7FFFu + ((u >> 16) & 1u);
    return (unsigned short)(u >> 16);
}

#define GLB_AS(p) ((const __attribute__((address_space(1))) unsigned int*)(p))
#define LDS_AS(p) ((__attribute__((address_space(3))) unsigned int*)(p))

// 16x16x16 bf16 MFMA: builtin if available, else raw encoding via inline asm.
__device__ __forceinline__ f32x4 mfma16x16(short4v a, short4v b, f32x4 c) {
#if __has_builtin(__builtin_amdgcn_mfma_f32_16x16x16bf16_1k)
    return __builtin_amdgcn_mfma_f32_16x16x16bf16_1k(a, b, c, 0, 0, 0);
#else
    asm("v_mfma_f32_16x16x16_bf16 %0, %1, %2, %0" : "+v"(c) : "v"(a), "v"(b));
    return c;
#endif
}

// ---- Prepass A: invgn[b][m] = 1/max(||g[b][:,m]||, 1e-8). grid (M/64, B), 256 thr ----
__global__ __launch_bounds__(256) void k_norm(const float* __restrict__ g,
                                              float* __restrict__ invgn) {
    __shared__ float red[4][64];
    const int b = blockIdx.y, m0 = blockIdx.x * 64;
    const int tid = threadIdx.x;
    const int ml = tid & 63, cq = tid >> 6;     // cq in [0,4)
    const float* gb = g + (size_t)b * C_ * M_ + m0 + ml;
    float ss = 0.f;
#pragma unroll 8
    for (int i = 0; i < 64; ++i) {
        float v = gb[(size_t)(cq * 64 + i) * M_];
        ss += v * v;
    }
    red[cq][ml] = ss;
    __syncthreads();
    if (cq == 0) {
        float t = red[0][ml] + red[1][ml] + red[2][ml] + red[3][ml];
        invgn[b * M_ + m0 + ml] = 1.f / fmaxf(sqrtf(t), 1e-8f);
    }
}

// ---- Prepass B: gcm = bf16(g)[c][m]; gmc = bf16(g*invgn)[m][c]. grid (M/64, C/64, B) ----
__global__ __launch_bounds__(256) void k_cast(const float* __restrict__ g,
                                              const float* __restrict__ invgn,
                                              unsigned short* __restrict__ gcm,
                                              unsigned short* __restrict__ gmc) {
    __shared__ unsigned short T[64 * 66];   // normalized [c][m] tile, odd-dword stride
    __shared__ float sInv[64];
    const int b = blockIdx.z, c0 = blockIdx.y * 64, m0 = blockIdx.x * 64;
    const int tid = threadIdx.x;
    if (tid < 64) sInv[tid] = invgn[b * M_ + m0 + tid];
    __syncthreads();
    const float* gbase = g + ((size_t)b * C_ + c0) * M_ + m0;
    unsigned short* gcmb = gcm + ((size_t)b * C_ + c0) * M_ + m0;
#pragma unroll
    for (int j = 0; j < 4; ++j) {
        int id = tid + 256 * j;                 // 1024 float4-chunks
        int ci = id >> 4, mq = (id & 15) * 4;
        float4 v = *(const float4*)(gbase + (size_t)ci * M_ + mq);
        uint2 pk;
        pk.x = (unsigned)f2bf(v.x) | ((unsigned)f2bf(v.y) << 16);
        pk.y = (unsigned)f2bf(v.z) | ((unsigned)f2bf(v.w) << 16);
        *(uint2*)(gcmb + (size_t)ci * M_ + mq) = pk;
        T[ci * 66 + mq + 0] = f2bf(v.x * sInv[mq + 0]);
        T[ci * 66 + mq + 1] = f2bf(v.y * sInv[mq + 1]);
        T[ci * 66 + mq + 2] = f2bf(v.z * sInv[mq + 2]);
        T[ci * 66 + mq + 3] = f2bf(v.w * sInv[mq + 3]);
    }
    __syncthreads();
    unsigned short* gmcb = gmc + ((size_t)b * M_ + m0) * C_ + c0;
#pragma unroll
    for (int j = 0; j < 2; ++j) {
        int id = tid + 256 * j;                 // 512 8-short chunks
        int mr = id >> 3, cc8 = (id & 7) * 8;
        U16x8 t;
#pragma unroll
        for (int k = 0; k < 8; ++k) t.us[k] = T[(cc8 + k) * 66 + mr];
        *(uint4*)(gmcb + (size_t)mr * C_ + cc8) = t.u4;
    }
}

// ---------------- Main fused kernel (v8) ----------------
// v7 key-split structure + batch-clustered XCD swizzle.
// Flat 512-block grid; HW round-robins linear block id across the 8 XCDs, so
// b = (bid&7)>>1 pins each batch to 2 XCDs. Per-XCD streaming working set =
// gmc_b + gcm_b = 2 MB < 4 MB L2 -> the 1 GB of global_load_lds traffic is
// served from L2 (~34.5 TB/s agg) instead of L3/HBM.
// Wave w owns keys [16w,16w+16) of each 64-key tile. GEMM1 computes
// S^T = mfma(ghat, qhat) so each lane holds P at (row=lane&15, key=quad*4+r) --
// exactly the 16x16x16 A-frag layout: P never touches LDS. GEMM2 accumulates
// per-wave partial O[32][256]; 3-round XOR exchange sums the 4 key-partials
// (each round adds a pristine partner block -- waves only modify their own
// block group, so the reduction is exact).
__global__ __launch_bounds__(256, 2) void k_main(
    const float* __restrict__ l,
    const unsigned short* __restrict__ gcm,    // [B][C][M] raw bf16   (GEMM2 B, k=m contig)
    const unsigned short* __restrict__ gmc,    // [B][M][C] normalized (GEMM1 A, k=c contig)
    float* __restrict__ out)
{
    __shared__ __align__(16) unsigned short sGmc[64 * 256];   // ghat [m][c], 32 KB
    __shared__ __align__(16) unsigned short sGcm[256 * 64];   // graw [c][m], 32 KB
    __shared__ float sDenW[4][32];                            // per-wave denom partials

    const int tid = threadIdx.x;
    const int w = tid >> 6;
    const int lane = tid & 63;
    const int l15 = lane & 15;
    const int quad = lane >> 4;

    // ---- batch-clustered XCD swizzle (bijective over 512 blocks) ----
    const int bid = blockIdx.x;
    const int xcd = bid & 7;
    const int b = xcd >> 1;                                   // 2 XCDs per batch
    const int row0 = (((bid >> 3) << 1) | (xcd & 1)) * 32;    // row-tile in [0,128)

    // per-lane DMA source offsets (shorts), XOR chunk swizzles match the read patterns
    int goffA[8], goffB[8];
#pragma unroll
    for (int i = 0; i < 8; ++i) {
        int p = (w * 8 + i) * 64 + lane;
        int rA = p >> 5;                                   // row in [0,64), 32 granules/row
        goffA[i] = rA * 256 + (((p & 31) ^ (rA & 31)) << 3);
        int rB = p >> 3;                                   // row in [0,256), 8 granules/row
        goffB[i] = rB * 2048 + (((p & 7) ^ ((rB >> 1) & 7)) << 3);
    }

    const unsigned short* gmc_b = gmc + (size_t)b * M_ * C_;
    const unsigned short* gcm_b = gcm + (size_t)b * C_ * M_;

    auto dmaA = [&](int m0) {
#pragma unroll
        for (int i = 0; i < 8; ++i)
            __builtin_amdgcn_global_load_lds(GLB_AS(gmc_b + (size_t)m0 * 256 + goffA[i]),
                                             LDS_AS(&sGmc[(w * 8 + i) * 512]), 16, 0, 0);
    };
    auto dmaB = [&](int m0) {
#pragma unroll
        for (int i = 0; i < 8; ++i)
            __builtin_amdgcn_global_load_lds(GLB_AS(gcm_b + (size_t)m0 + goffB[i]),
                                             LDS_AS(&sGcm[(w * 8 + i) * 512]), 16, 0, 0);
    };

    dmaA(0);
    dmaB(0);

    // ---- Q: ALL 32 rows per wave (B-operand frags), row norm, normalize -> bf16 ----
    short8 qf[2][8];
#pragma unroll
    for (int rt = 0; rt < 2; ++rt) {
        const float* lrow = l + ((size_t)b * N_ + row0 + rt * 16 + l15) * C_;
        U16x8 qt[8];
        float ss = 0.f;
#pragma unroll
        for (int kk = 0; kk < 8; ++kk) {
            float4 x0 = *(const float4*)(lrow + kk * 32 + quad * 8);
            float4 x1 = *(const float4*)(lrow + kk * 32 + quad * 8 + 4);
            ss += x0.x*x0.x + x0.y*x0.y + x0.z*x0.z + x0.w*x0.w;
            ss += x1.x*x1.x + x1.y*x1.y + x1.z*x1.z + x1.w*x1.w;
            qt[kk].us[0] = f2bf(x0.x); qt[kk].us[1] = f2bf(x0.y);
            qt[kk].us[2] = f2bf(x0.z); qt[kk].us[3] = f2bf(x0.w);
            qt[kk].us[4] = f2bf(x1.x); qt[kk].us[5] = f2bf(x1.y);
            qt[kk].us[6] = f2bf(x1.z); qt[kk].us[7] = f2bf(x1.w);
        }
        ss += __shfl_xor(ss, 16);
        ss += __shfl_xor(ss, 32);
        const float invl = 1.0f / fmaxf(sqrtf(ss), 1e-8f);
#pragma unroll
        for (int kk = 0; kk < 8; ++kk) {
            U16x8 t;
#pragma unroll
            for (int j = 0; j < 8; ++j) t.us[j] = f2bf(bf2f(qt[kk].us[j]) * invl);
            qf[rt][kk] = t.s8;
        }
    }

    __syncthreads();   // drains DMA(tile 0)

    f32x4 zero = {0.f, 0.f, 0.f, 0.f};
    f32x4 o[2][16];    // per-wave PARTIAL O (its 16 keys): [row-tile][c-tile 16c]
#pragma unroll
    for (int i = 0; i < 2; ++i)
#pragma unroll
        for (int j = 0; j < 16; ++j) o[i][j] = zero;
    float dl0 = 0.f, dl1 = 0.f;

    // GEMM1 A-frag source: my 16 key-rows of sGmc
    const unsigned short* gAbase = &sGmc[(w * 16 + l15) * 256];
    const int rxor = (w * 16 + l15) & 31;
    // GEMM2 B-frag source: chunk-of-4 XOR swizzle (matches goffB granule swizzle)
    const int chunkXor = (w * 4 + quad) ^ (l15 & 14);
    const unsigned short* gBbase = &sGcm[l15 * 64 + (chunkXor << 2)];

    for (int mt = 0; mt < 32; ++mt) {
        // GEMM1 (swapped): S^T[16 keys][16 rows] per row-tile, K=256
        f32x4 sa0 = zero, sa1 = zero;
#pragma unroll
        for (int kk = 0; kk < 8; ++kk) {
            short8 ag = *(const short8*)&gAbase[((kk * 4 + quad) ^ rxor) << 3];
            sa0 = __builtin_amdgcn_mfma_f32_16x16x32_bf16(ag, qf[0][kk], sa0, 0, 0, 0);
            sa1 = __builtin_amdgcn_mfma_f32_16x16x32_bf16(ag, qf[1][kk], sa1, 0, 0, 0);
        }
        // p = exp(cos/tau); lane holds (row = rt*16+l15, key = quad*4+r) -> already
        // the 16x16x16 A-frag layout. Accumulate denominator partials.
        U16x4 pk0, pk1;
#pragma unroll
        for (int r = 0; r < 4; ++r) {
            float p0 = exp2f(sa0[r] * 3.6067376022224085f);
            float p1 = exp2f(sa1[r] * 3.6067376022224085f);
            dl0 += p0; dl1 += p1;
            pk0.us[r] = f2bf(p0);
            pk1.us[r] = f2bf(p1);
        }
        __syncthreads();                    // barrier A: sGmc readers done, dmaB drained
        if (mt < 31) dmaA((mt + 1) * 64);   // covered by GEMM2, drained at barrier B

        // GEMM2 key-split: O_partial[32 rows][256 c] += P[32][16 keys] * V[16][256]
#pragma unroll
        for (int ct = 0; ct < 16; ++ct) {
            short4v bb = *(const short4v*)&gBbase[ct * 1024];
            o[0][ct] = mfma16x16(pk0.s4, bb, o[0][ct]);
            o[1][ct] = mfma16x16(pk1.s4, bb, o[1][ct]);
        }
        __syncthreads();                    // barrier B: sGcm readers done, dmaA drained
        if (mt < 31) dmaB((mt + 1) * 64);   // covered by next GEMM1, drained at barrier A
    }

    // ---- denominators: quad-reduce, publish per-wave partial per row ----
    {
        float d0 = dl0;
        d0 += __shfl_xor(d0, 16);
        d0 += __shfl_xor(d0, 32);
        float d1 = dl1;
        d1 += __shfl_xor(d1, 16);
        d1 += __shfl_xor(d1, 32);
        if (quad == 0) {
            sDenW[w][l15] = d0;
            sDenW[w][16 + l15] = d1;
        }
    }

    // ---- O reduction: 3 XOR rounds through 32 KB f32 buffer (reuse sGmc) ----
    float* red = (float*)sGmc;
#pragma unroll
    for (int rnd = 1; rnd < 4; ++rnd) {
        __syncthreads();                    // rnd 1: loop reads done; else: prev round reads done
        const int dw = w ^ rnd;
#pragma unroll
        for (int rt = 0; rt < 2; ++rt)
#pragma unroll
            for (int i = 0; i < 4; ++i)
                *(f32x4*)&red[dw * 2048 + (((rt * 4 + i) * 4 + quad) * 16 + l15) * 4] =
                    o[rt][4 * dw + i];
        __syncthreads();
#pragma unroll
        for (int rt = 0; rt < 2; ++rt)
#pragma unroll
            for (int i = 0; i < 4; ++i) {
                f32x4 v = *(const f32x4*)&red[w * 2048 + (((rt * 4 + i) * 4 + quad) * 16 + l15) * 4];
                o[rt][4 * w + i] += v;
            }
    }

    // ---- epilogue: wave w owns c in [64w, 64w+64). out = l + O/denom ----
    const float* lb = l + ((size_t)b * N_ + row0) * C_;
    float* ob = out + ((size_t)b * N_ + row0) * C_;
#pragma unroll
    for (int rt = 0; rt < 2; ++rt) {
#pragma unroll
        for (int r = 0; r < 4; ++r) {
            const int row = rt * 16 + quad * 4 + r;
            const float den = sDenW[0][row] + sDenW[1][row] + sDenW[2][row] + sDenW[3][row];
            const float inv = 1.f / den;
            const size_t rbase = (size_t)row * C_;
#pragma unroll
            for (int i = 0; i < 4; ++i) {
                const int c = w * 64 + i * 16 + l15;
                ob[rbase + c] = lb[rbase + c] + o[rt][4 * w + i][r] * inv;
            }
        }
    }
}

extern "C" void kernel_launch(void* const* d_in, const int* in_sizes, int n_in,
                              void* d_out, int out_size, void* d_ws, size_t ws_size,
                              hipStream_t stream) {
    (void)in_sizes; (void)n_in; (void)out_size; (void)ws_size;
    const float* l = (const float*)d_in[0];
    const float* g = (const float*)d_in[1];
    float* outp = (float*)d_out;

    char* ws = (char*)d_ws;
    unsigned short* gmc = (unsigned short*)ws;                                   // 4 MB (normalized, [b][m][c])
    unsigned short* gcm = (unsigned short*)(ws + (size_t)B_ * M_ * C_ * 2);      // 4 MB (raw, [b][c][m])
    float* invgn = (float*)(ws + 2 * (size_t)B_ * M_ * C_ * 2);                  // 32 KB

    k_norm<<<dim3(M_ / 64, B_), 256, 0, stream>>>(g, invgn);
    k_cast<<<dim3(M_ / 64, C_ / 64, B_), 256, 0, stream>>>(g, invgn, gcm, gmc);
    k_main<<<dim3(N_ / 32 * B_), 256, 0, stream>>>(l, gcm, gmc, outp);
}

// Round 3
// 144.912 us; speedup vs baseline: 4.8150x; 4.8150x over previous
//
#include <hip/hip_runtime.h>

#define B_ 4
#define N_ 4096
#define C_ 256
#define M_ 2048

typedef __attribute__((ext_vector_type(8))) short short8;
typedef __attribute__((ext_vector_type(4))) short short4v;
typedef __attribute__((ext_vector_type(4))) float f32x4;

union U16x8 { uint4 u4; unsigned short us[8]; short8 s8; };
union U16x4 { uint2 u2; unsigned short us[4]; short4v s4; };

__device__ __forceinline__ float bf2f(unsigned short h) {
    unsigned int u = ((unsigned int)h) << 16;
    return __builtin_bit_cast(float, u);
}
__device__ __forceinline__ unsigned short f2bf(float f) {
    unsigned int u = __builtin_bit_cast(unsigned int, f);
    u += 0x7FFFu + ((u >> 16) & 1u);
    return (unsigned short)(u >> 16);
}

#define GLB_AS(p) ((const __attribute__((address_space(1))) unsigned int*)(p))
#define LDS_AS(p) ((__attribute__((address_space(3))) unsigned int*)(p))

// 16x16x16 bf16 MFMA: builtin if available, else raw encoding via inline asm.
__device__ __forceinline__ f32x4 mfma16x16(short4v a, short4v b, f32x4 c) {
#if __has_builtin(__builtin_amdgcn_mfma_f32_16x16x16bf16_1k)
    return __builtin_amdgcn_mfma_f32_16x16x16bf16_1k(a, b, c, 0, 0, 0);
#else
    asm("v_mfma_f32_16x16x16_bf16 %0, %1, %2, %0" : "+v"(c) : "v"(a), "v"(b));
    return c;
#endif
}

// ---- Prepass A: invgn[b][m] = 1/max(||g[b][:,m]||, 1e-8). grid (M/64, B), 256 thr ----
__global__ __launch_bounds__(256) void k_norm(const float* __restrict__ g,
                                              float* __restrict__ invgn) {
    __shared__ float red[4][64];
    const int b = blockIdx.y, m0 = blockIdx.x * 64;
    const int tid = threadIdx.x;
    const int ml = tid & 63, cq = tid >> 6;     // cq in [0,4)
    const float* gb = g + (size_t)b * C_ * M_ + m0 + ml;
    float ss = 0.f;
#pragma unroll 8
    for (int i = 0; i < 64; ++i) {
        float v = gb[(size_t)(cq * 64 + i) * M_];
        ss += v * v;
    }
    red[cq][ml] = ss;
    __syncthreads();
    if (cq == 0) {
        float t = red[0][ml] + red[1][ml] + red[2][ml] + red[3][ml];
        invgn[b * M_ + m0 + ml] = 1.f / fmaxf(sqrtf(t), 1e-8f);
    }
}

// ---- Prepass B: gcm = bf16(g)[c][m]; gmc = bf16(g*invgn)[m][c]. grid (M/64, C/64, B) ----
__global__ __launch_bounds__(256) void k_cast(const float* __restrict__ g,
                                              const float* __restrict__ invgn,
                                              unsigned short* __restrict__ gcm,
                                              unsigned short* __restrict__ gmc) {
    __shared__ unsigned short T[64 * 66];   // normalized [c][m] tile, odd-dword stride
    __shared__ float sInv[64];
    const int b = blockIdx.z, c0 = blockIdx.y * 64, m0 = blockIdx.x * 64;
    const int tid = threadIdx.x;
    if (tid < 64) sInv[tid] = invgn[b * M_ + m0 + tid];
    __syncthreads();
    const float* gbase = g + ((size_t)b * C_ + c0) * M_ + m0;
    unsigned short* gcmb = gcm + ((size_t)b * C_ + c0) * M_ + m0;
#pragma unroll
    for (int j = 0; j < 4; ++j) {
        int id = tid + 256 * j;                 // 1024 float4-chunks
        int ci = id >> 4, mq = (id & 15) * 4;
        float4 v = *(const float4*)(gbase + (size_t)ci * M_ + mq);
        uint2 pk;
        pk.x = (unsigned)f2bf(v.x) | ((unsigned)f2bf(v.y) << 16);
        pk.y = (unsigned)f2bf(v.z) | ((unsigned)f2bf(v.w) << 16);
        *(uint2*)(gcmb + (size_t)ci * M_ + mq) = pk;
        T[ci * 66 + mq + 0] = f2bf(v.x * sInv[mq + 0]);
        T[ci * 66 + mq + 1] = f2bf(v.y * sInv[mq + 1]);
        T[ci * 66 + mq + 2] = f2bf(v.z * sInv[mq + 2]);
        T[ci * 66 + mq + 3] = f2bf(v.w * sInv[mq + 3]);
    }
    __syncthreads();
    unsigned short* gmcb = gmc + ((size_t)b * M_ + m0) * C_ + c0;
#pragma unroll
    for (int j = 0; j < 2; ++j) {
        int id = tid + 256 * j;                 // 512 8-short chunks
        int mr = id >> 3, cc8 = (id & 7) * 8;
        U16x8 t;
#pragma unroll
        for (int k = 0; k < 8; ++k) t.us[k] = T[(cc8 + k) * 66 + mr];
        *(uint4*)(gmcb + (size_t)mr * C_ + cc8) = t.u4;
    }
}

// ---------------- Main fused kernel (v9) ----------------
// v8 structure (key-split waves, P stays in registers, batch-clustered XCD
// swizzle) with the scratch-spill bug fixed: EVERY access to the accumulator
// array `o` is now compile-time static (rule #20 -- v8's runtime-indexed
// o[rt][4*w+i] demoted all 128 accumulator VGPRs to scratch: 2.2 GB WRITE_SIZE,
// VGPR_Count=112, 4.5x slowdown). The 4-way key-partial reduction is now a
// 2-pass full LDS dump (64 KB buffer aliasing sGmc+sGcm, safe after loop exit)
// with statically-unrolled indices on both sides.
__global__ __launch_bounds__(256, 2) void k_main(
    const float* __restrict__ l,
    const unsigned short* __restrict__ gcm,    // [B][C][M] raw bf16   (GEMM2 B, k=m contig)
    const unsigned short* __restrict__ gmc,    // [B][M][C] normalized (GEMM1 A, k=c contig)
    float* __restrict__ out)
{
    __shared__ __align__(16) char sMem[66048];
    unsigned short* sGmc = (unsigned short*)sMem;              // ghat [m][c], 32 KB
    unsigned short* sGcm = (unsigned short*)(sMem + 32768);    // graw [c][m], 32 KB
    float (*sDenW)[32] = (float (*)[32])(sMem + 65536);        // [4][32] denom partials

    const int tid = threadIdx.x;
    const int w = tid >> 6;
    const int lane = tid & 63;
    const int l15 = lane & 15;
    const int quad = lane >> 4;

    // ---- batch-clustered XCD swizzle (bijective over 512 blocks) ----
    const int bid = blockIdx.x;
    const int xcd = bid & 7;
    const int b = xcd >> 1;                                   // 2 XCDs per batch
    const int row0 = (((bid >> 3) << 1) | (xcd & 1)) * 32;    // row-tile in [0,128)

    // per-lane DMA source offsets (shorts), XOR chunk swizzles match the read patterns
    int goffA[8], goffB[8];
#pragma unroll
    for (int i = 0; i < 8; ++i) {
        int p = (w * 8 + i) * 64 + lane;
        int rA = p >> 5;                                   // row in [0,64), 32 granules/row
        goffA[i] = rA * 256 + (((p & 31) ^ (rA & 31)) << 3);
        int rB = p >> 3;                                   // row in [0,256), 8 granules/row
        goffB[i] = rB * 2048 + (((p & 7) ^ ((rB >> 1) & 7)) << 3);
    }

    const unsigned short* gmc_b = gmc + (size_t)b * M_ * C_;
    const unsigned short* gcm_b = gcm + (size_t)b * C_ * M_;

    auto dmaA = [&](int m0) {
#pragma unroll
        for (int i = 0; i < 8; ++i)
            __builtin_amdgcn_global_load_lds(GLB_AS(gmc_b + (size_t)m0 * 256 + goffA[i]),
                                             LDS_AS(&sGmc[(w * 8 + i) * 512]), 16, 0, 0);
    };
    auto dmaB = [&](int m0) {
#pragma unroll
        for (int i = 0; i < 8; ++i)
            __builtin_amdgcn_global_load_lds(GLB_AS(gcm_b + (size_t)m0 + goffB[i]),
                                             LDS_AS(&sGcm[(w * 8 + i) * 512]), 16, 0, 0);
    };

    dmaA(0);
    dmaB(0);

    // ---- Q: ALL 32 rows per wave (B-operand frags), row norm, normalize -> bf16 ----
    short8 qf[2][8];
#pragma unroll
    for (int rt = 0; rt < 2; ++rt) {
        const float* lrow = l + ((size_t)b * N_ + row0 + rt * 16 + l15) * C_;
        U16x8 qt[8];
        float ss = 0.f;
#pragma unroll
        for (int kk = 0; kk < 8; ++kk) {
            float4 x0 = *(const float4*)(lrow + kk * 32 + quad * 8);
            float4 x1 = *(const float4*)(lrow + kk * 32 + quad * 8 + 4);
            ss += x0.x*x0.x + x0.y*x0.y + x0.z*x0.z + x0.w*x0.w;
            ss += x1.x*x1.x + x1.y*x1.y + x1.z*x1.z + x1.w*x1.w;
            qt[kk].us[0] = f2bf(x0.x); qt[kk].us[1] = f2bf(x0.y);
            qt[kk].us[2] = f2bf(x0.z); qt[kk].us[3] = f2bf(x0.w);
            qt[kk].us[4] = f2bf(x1.x); qt[kk].us[5] = f2bf(x1.y);
            qt[kk].us[6] = f2bf(x1.z); qt[kk].us[7] = f2bf(x1.w);
        }
        ss += __shfl_xor(ss, 16);
        ss += __shfl_xor(ss, 32);
        const float invl = 1.0f / fmaxf(sqrtf(ss), 1e-8f);
#pragma unroll
        for (int kk = 0; kk < 8; ++kk) {
            U16x8 t;
#pragma unroll
            for (int j = 0; j < 8; ++j) t.us[j] = f2bf(bf2f(qt[kk].us[j]) * invl);
            qf[rt][kk] = t.s8;
        }
    }

    __syncthreads();   // drains DMA(tile 0)

    f32x4 zero = {0.f, 0.f, 0.f, 0.f};
    f32x4 o[2][16];    // per-wave PARTIAL O (its 16 keys): [row-tile][c-tile 16c]
#pragma unroll
    for (int i = 0; i < 2; ++i)
#pragma unroll
        for (int j = 0; j < 16; ++j) o[i][j] = zero;
    float dl0 = 0.f, dl1 = 0.f;

    // GEMM1 A-frag source: my 16 key-rows of sGmc
    const unsigned short* gAbase = &sGmc[(w * 16 + l15) * 256];
    const int rxor = (w * 16 + l15) & 31;
    // GEMM2 B-frag source: chunk-of-4 XOR swizzle (matches goffB granule swizzle)
    const int chunkXor = (w * 4 + quad) ^ (l15 & 14);
    const unsigned short* gBbase = &sGcm[l15 * 64 + (chunkXor << 2)];

    for (int mt = 0; mt < 32; ++mt) {
        // GEMM1 (swapped): S^T[16 keys][16 rows] per row-tile, K=256
        f32x4 sa0 = zero, sa1 = zero;
#pragma unroll
        for (int kk = 0; kk < 8; ++kk) {
            short8 ag = *(const short8*)&gAbase[((kk * 4 + quad) ^ rxor) << 3];
            sa0 = __builtin_amdgcn_mfma_f32_16x16x32_bf16(ag, qf[0][kk], sa0, 0, 0, 0);
            sa1 = __builtin_amdgcn_mfma_f32_16x16x32_bf16(ag, qf[1][kk], sa1, 0, 0, 0);
        }
        // p = exp(cos/tau); lane holds (row = rt*16+l15, key = quad*4+r) -> already
        // the 16x16x16 A-frag layout. Accumulate denominator partials.
        U16x4 pk0, pk1;
#pragma unroll
        for (int r = 0; r < 4; ++r) {
            float p0 = exp2f(sa0[r] * 3.6067376022224085f);
            float p1 = exp2f(sa1[r] * 3.6067376022224085f);
            dl0 += p0; dl1 += p1;
            pk0.us[r] = f2bf(p0);
            pk1.us[r] = f2bf(p1);
        }
        __syncthreads();                    // barrier A: sGmc readers done, dmaB drained
        if (mt < 31) dmaA((mt + 1) * 64);   // covered by GEMM2, drained at barrier B

        // GEMM2 key-split: O_partial[32 rows][256 c] += P[32][16 keys] * V[16][256]
#pragma unroll
        for (int ct = 0; ct < 16; ++ct) {
            short4v bb = *(const short4v*)&gBbase[ct * 1024];
            o[0][ct] = mfma16x16(pk0.s4, bb, o[0][ct]);
            o[1][ct] = mfma16x16(pk1.s4, bb, o[1][ct]);
        }
        __syncthreads();                    // barrier B: sGcm/sP readers done, dmaA drained
        if (mt < 31) dmaB((mt + 1) * 64);   // covered by next GEMM1, drained at barrier A
    }

    // ---- denominators: quad-reduce, publish per-wave partial per row ----
    {
        float d0 = dl0;
        d0 += __shfl_xor(d0, 16);
        d0 += __shfl_xor(d0, 32);
        float d1 = dl1;
        d1 += __shfl_xor(d1, 16);
        d1 += __shfl_xor(d1, 32);
        if (quad == 0) {
            sDenW[w][l15] = d0;
            sDenW[w][16 + l15] = d1;
        }
    }

    // ---- O reduction: 2-pass full LDS dump, ALL indices static (rule #20) ----
    // slot(sw, ct, quad, l15) = sw*1024 + ct*64 + quad*16 + l15   (f32x4 units, 64 KB)
    // Wave writes are 1 KB contiguous per ct -> conflict-free; reads likewise.
    f32x4* red = (f32x4*)sMem;
    const int wbase = w * 1024 + quad * 16 + l15;      // + ct*64
    const int rbase0 = (4 * w) * 64 + quad * 16 + l15; // + jj*64 + sw*1024
    f32x4 oacc0[4], oacc1[4];

    __syncthreads();   // all loop LDS reads done; sDenW visible; safe to overwrite sMem
    // pass 1: row-tile 0
#pragma unroll
    for (int j = 0; j < 16; ++j) red[wbase + j * 64] = o[0][j];
    __syncthreads();
#pragma unroll
    for (int jj = 0; jj < 4; ++jj) {
        const int base = rbase0 + jj * 64;
        oacc0[jj] = red[base] + red[base + 1024] + red[base + 2048] + red[base + 3072];
    }
    __syncthreads();   // pass-1 reads done
    // pass 2: row-tile 1
#pragma unroll
    for (int j = 0; j < 16; ++j) red[wbase + j * 64] = o[1][j];
    __syncthreads();
#pragma unroll
    for (int jj = 0; jj < 4; ++jj) {
        const int base = rbase0 + jj * 64;
        oacc1[jj] = red[base] + red[base + 1024] + red[base + 2048] + red[base + 3072];
    }

    // ---- epilogue: wave w owns c in [64w, 64w+64). out = l + O/denom ----
    const float* lb = l + ((size_t)b * N_ + row0) * C_;
    float* ob = out + ((size_t)b * N_ + row0) * C_;
#pragma unroll
    for (int r = 0; r < 4; ++r) {
        {   // row-tile 0
            const int row = quad * 4 + r;
            const float inv = 1.f / (sDenW[0][row] + sDenW[1][row] + sDenW[2][row] + sDenW[3][row]);
            const size_t rb = (size_t)row * C_;
#pragma unroll
            for (int jj = 0; jj < 4; ++jj) {
                const int c = w * 64 + jj * 16 + l15;
                ob[rb + c] = lb[rb + c] + oacc0[jj][r] * inv;
            }
        }
        {   // row-tile 1
            const int row = 16 + quad * 4 + r;
            const float inv = 1.f / (sDenW[0][row] + sDenW[1][row] + sDenW[2][row] + sDenW[3][row]);
            const size_t rb = (size_t)row * C_;
#pragma unroll
            for (int jj = 0; jj < 4; ++jj) {
                const int c = w * 64 + jj * 16 + l15;
                ob[rb + c] = lb[rb + c] + oacc1[jj][r] * inv;
            }
        }
    }
}

extern "C" void kernel_launch(void* const* d_in, const int* in_sizes, int n_in,
                              void* d_out, int out_size, void* d_ws, size_t ws_size,
                              hipStream_t stream) {
    (void)in_sizes; (void)n_in; (void)out_size; (void)ws_size;
    const float* l = (const float*)d_in[0];
    const float* g = (const float*)d_in[1];
    float* outp = (float*)d_out;

    char* ws = (char*)d_ws;
    unsigned short* gmc = (unsigned short*)ws;                                   // 4 MB (normalized, [b][m][c])
    unsigned short* gcm = (unsigned short*)(ws + (size_t)B_ * M_ * C_ * 2);      // 4 MB (raw, [b][c][m])
    float* invgn = (float*)(ws + 2 * (size_t)B_ * M_ * C_ * 2);                  // 32 KB

    k_norm<<<dim3(M_ / 64, B_), 256, 0, stream>>>(g, invgn);
    k_cast<<<dim3(M_ / 64, C_ / 64, B_), 256, 0, stream>>>(g, invgn, gcm, gmc);
    k_main<<<dim3(N_ / 32 * B_), 256, 0, stream>>>(l, gcm, gmc, outp);
}

// Round 4
// 139.727 us; speedup vs baseline: 4.9937x; 1.0371x over previous
//
#include <hip/hip_runtime.h>

#define B_ 4
#define N_ 4096
#define C_ 256
#define M_ 2048

typedef __attribute__((ext_vector_type(8))) short short8;
typedef __attribute__((ext_vector_type(4))) short short4v;
typedef __attribute__((ext_vector_type(4))) float f32x4;

union U16x8 { uint4 u4; unsigned short us[8]; short8 s8; };
union U16x4 { uint2 u2; unsigned short us[4]; short4v s4; };

__device__ __forceinline__ float bf2f(unsigned short h) {
    unsigned int u = ((unsigned int)h) << 16;
    return __builtin_bit_cast(float, u);
}
__device__ __forceinline__ unsigned short f2bf(float f) {
    unsigned int u = __builtin_bit_cast(unsigned int, f);
    u += 0x7FFFu + ((u >> 16) & 1u);
    return (unsigned short)(u >> 16);
}

#define GLB_AS(p) ((const __attribute__((address_space(1))) unsigned int*)(p))
#define LDS_AS(p) ((__attribute__((address_space(3))) unsigned int*)(p))

// 16x16x16 bf16 MFMA: builtin if available, else raw encoding via inline asm.
__device__ __forceinline__ f32x4 mfma16x16(short4v a, short4v b, f32x4 c) {
#if __has_builtin(__builtin_amdgcn_mfma_f32_16x16x16bf16_1k)
    return __builtin_amdgcn_mfma_f32_16x16x16bf16_1k(a, b, c, 0, 0, 0);
#else
    asm("v_mfma_f32_16x16x16_bf16 %0, %1, %2, %0" : "+v"(c) : "v"(a), "v"(b));
    return c;
#endif
}

// ---- Fused prepass: norms + casts. grid (M/64, B), 256 thr ----
// Phase 1 (k_norm body): column sum-squares -> sInv[m] in LDS.
// Phase 2 (k_cast body x4 c-tiles): re-read g (L2-warm from phase 1),
// write gcm = bf16(g) [c][m] and gmc = bf16(g*invgn) [m][c].
__global__ __launch_bounds__(256) void k_prep(const float* __restrict__ g,
                                              unsigned short* __restrict__ gcm,
                                              unsigned short* __restrict__ gmc) {
    __shared__ float red[4][64];
    __shared__ float sInv[64];
    __shared__ unsigned short T[64 * 66];   // normalized [c][m] tile, odd-dword stride
    const int b = blockIdx.y, m0 = blockIdx.x * 64;
    const int tid = threadIdx.x;
    const int ml = tid & 63, cq = tid >> 6;     // cq in [0,4)

    // phase 1: norms
    const float* gb = g + (size_t)b * C_ * M_ + m0 + ml;
    float ss = 0.f;
#pragma unroll 8
    for (int i = 0; i < 64; ++i) {
        float v = gb[(size_t)(cq * 64 + i) * M_];
        ss += v * v;
    }
    red[cq][ml] = ss;
    __syncthreads();
    if (cq == 0) {
        float t = red[0][ml] + red[1][ml] + red[2][ml] + red[3][ml];
        sInv[ml] = 1.f / fmaxf(sqrtf(t), 1e-8f);
    }
    __syncthreads();

    // phase 2: casts, 4 c-tiles of 64
    for (int c0 = 0; c0 < C_; c0 += 64) {
        const float* gbase = g + ((size_t)b * C_ + c0) * M_ + m0;
        unsigned short* gcmb = gcm + ((size_t)b * C_ + c0) * M_ + m0;
#pragma unroll
        for (int j = 0; j < 4; ++j) {
            int id = tid + 256 * j;                 // 1024 float4-chunks
            int ci = id >> 4, mq = (id & 15) * 4;
            float4 v = *(const float4*)(gbase + (size_t)ci * M_ + mq);
            uint2 pk;
            pk.x = (unsigned)f2bf(v.x) | ((unsigned)f2bf(v.y) << 16);
            pk.y = (unsigned)f2bf(v.z) | ((unsigned)f2bf(v.w) << 16);
            *(uint2*)(gcmb + (size_t)ci * M_ + mq) = pk;
            T[ci * 66 + mq + 0] = f2bf(v.x * sInv[mq + 0]);
            T[ci * 66 + mq + 1] = f2bf(v.y * sInv[mq + 1]);
            T[ci * 66 + mq + 2] = f2bf(v.z * sInv[mq + 2]);
            T[ci * 66 + mq + 3] = f2bf(v.w * sInv[mq + 3]);
        }
        __syncthreads();
        unsigned short* gmcb = gmc + ((size_t)b * M_ + m0) * C_ + c0;
#pragma unroll
        for (int j = 0; j < 2; ++j) {
            int id = tid + 256 * j;                 // 512 8-short chunks
            int mr = id >> 3, cc8 = (id & 7) * 8;
            U16x8 t;
#pragma unroll
            for (int k = 0; k < 8; ++k) t.us[k] = T[(cc8 + k) * 66 + mr];
            *(uint4*)(gmcb + (size_t)mr * C_ + cc8) = t.u4;
        }
        __syncthreads();   // T reused next tile
    }
}

// ---------------- Main fused kernel (v10) ----------------
// 64 query rows / block, 8 waves (512 thr), 256 blocks = 1/CU (zero tail).
// Wave (kh = w&3, rh = w>>2): keys [16kh,16kh+16), rows [32rh, 32rh+32).
// Per-wave structure identical to v9 (Q 64 VGPR, P in regs via swapped GEMM1,
// o[2][16] accumulators) but the block covers 2x rows -> g streamed once per
// 64 rows: total restream 1 GB -> 512 MB; per-CU LDS traffic 256->192 KB/iter.
// Key-partial reduction: 4 static rounds (rh x rt) through a 64 KB LDS dump
// (all indices compile-time; rule #20).
__global__ __launch_bounds__(512, 2) void k_main(
    const float* __restrict__ l,
    const unsigned short* __restrict__ gcm,    // [B][C][M] raw bf16   (GEMM2 B, k=m contig)
    const unsigned short* __restrict__ gmc,    // [B][M][C] normalized (GEMM1 A, k=c contig)
    float* __restrict__ out)
{
    __shared__ __align__(16) char sMem[66560];
    unsigned short* sGmc = (unsigned short*)sMem;              // ghat [m][c], 32 KB
    unsigned short* sGcm = (unsigned short*)(sMem + 32768);    // graw [c][m], 32 KB
    float (*sDen)[64] = (float (*)[64])(sMem + 65536);         // [4 kh][64 rows]

    const int tid = threadIdx.x;
    const int w = tid >> 6;
    const int lane = tid & 63;
    const int l15 = lane & 15;
    const int quad = lane >> 4;
    const int kh = w & 3;        // key-quarter
    const int rh = w >> 2;       // row-half

    // ---- batch-clustered XCD swizzle (bijective over 256 blocks) ----
    const int bid = blockIdx.x;
    const int xcd = bid & 7;
    const int b = xcd >> 1;                                   // 2 XCDs per batch
    const int row0 = (((bid >> 3) << 1) | (xcd & 1)) * 64;    // 64-row tile in [0,4096)

    // per-lane DMA source offsets (shorts), XOR chunk swizzles match the read patterns
    int goffA[4], goffB[4];
#pragma unroll
    for (int i = 0; i < 4; ++i) {
        int p = (w * 4 + i) * 64 + lane;                   // p in [0,2048)
        int rA = p >> 5;                                   // row in [0,64), 32 granules/row
        goffA[i] = rA * 256 + (((p & 31) ^ (rA & 31)) << 3);
        int rB = p >> 3;                                   // row in [0,256), 8 granules/row
        goffB[i] = rB * 2048 + (((p & 7) ^ ((rB >> 1) & 7)) << 3);
    }

    const unsigned short* gmc_b = gmc + (size_t)b * M_ * C_;
    const unsigned short* gcm_b = gcm + (size_t)b * C_ * M_;

    auto dmaA = [&](int m0) {
#pragma unroll
        for (int i = 0; i < 4; ++i)
            __builtin_amdgcn_global_load_lds(GLB_AS(gmc_b + (size_t)m0 * 256 + goffA[i]),
                                             LDS_AS(&sGmc[(w * 4 + i) * 512]), 16, 0, 0);
    };
    auto dmaB = [&](int m0) {
#pragma unroll
        for (int i = 0; i < 4; ++i)
            __builtin_amdgcn_global_load_lds(GLB_AS(gcm_b + (size_t)m0 + goffB[i]),
                                             LDS_AS(&sGcm[(w * 4 + i) * 512]), 16, 0, 0);
    };

    dmaA(0);
    dmaB(0);

    // ---- Q: my 32 rows (row-half rh), row norm, normalize -> bf16 B-frags ----
    short8 qf[2][8];
#pragma unroll
    for (int rt = 0; rt < 2; ++rt) {
        const float* lrow = l + ((size_t)b * N_ + row0 + rh * 32 + rt * 16 + l15) * C_;
        U16x8 qt[8];
        float ss = 0.f;
#pragma unroll
        for (int kk = 0; kk < 8; ++kk) {
            float4 x0 = *(const float4*)(lrow + kk * 32 + quad * 8);
            float4 x1 = *(const float4*)(lrow + kk * 32 + quad * 8 + 4);
            ss += x0.x*x0.x + x0.y*x0.y + x0.z*x0.z + x0.w*x0.w;
            ss += x1.x*x1.x + x1.y*x1.y + x1.z*x1.z + x1.w*x1.w;
            qt[kk].us[0] = f2bf(x0.x); qt[kk].us[1] = f2bf(x0.y);
            qt[kk].us[2] = f2bf(x0.z); qt[kk].us[3] = f2bf(x0.w);
            qt[kk].us[4] = f2bf(x1.x); qt[kk].us[5] = f2bf(x1.y);
            qt[kk].us[6] = f2bf(x1.z); qt[kk].us[7] = f2bf(x1.w);
        }
        ss += __shfl_xor(ss, 16);
        ss += __shfl_xor(ss, 32);
        const float invl = 1.0f / fmaxf(sqrtf(ss), 1e-8f);
#pragma unroll
        for (int kk = 0; kk < 8; ++kk) {
            U16x8 t;
#pragma unroll
            for (int j = 0; j < 8; ++j) t.us[j] = f2bf(bf2f(qt[kk].us[j]) * invl);
            qf[rt][kk] = t.s8;
        }
    }

    __syncthreads();   // drains DMA(tile 0)

    f32x4 zero = {0.f, 0.f, 0.f, 0.f};
    f32x4 o[2][16];    // per-wave PARTIAL O (its 16 keys): [row-tile][c-tile 16c]
#pragma unroll
    for (int i = 0; i < 2; ++i)
#pragma unroll
        for (int j = 0; j < 16; ++j) o[i][j] = zero;
    float dl0 = 0.f, dl1 = 0.f;

    // GEMM1 A-frag source: my 16 key-rows of sGmc
    const unsigned short* gAbase = &sGmc[(kh * 16 + l15) * 256];
    const int rxor = (kh * 16 + l15) & 31;
    // GEMM2 B-frag source: chunk-of-4 XOR swizzle (matches goffB granule swizzle)
    const int chunkXor = (kh * 4 + quad) ^ (l15 & 14);
    const unsigned short* gBbase = &sGcm[l15 * 64 + (chunkXor << 2)];

    for (int mt = 0; mt < 32; ++mt) {
        // GEMM1 (swapped): S^T[16 keys][16 rows] per row-tile, K=256
        f32x4 sa0 = zero, sa1 = zero;
#pragma unroll
        for (int kk = 0; kk < 8; ++kk) {
            short8 ag = *(const short8*)&gAbase[((kk * 4 + quad) ^ rxor) << 3];
            sa0 = __builtin_amdgcn_mfma_f32_16x16x32_bf16(ag, qf[0][kk], sa0, 0, 0, 0);
            sa1 = __builtin_amdgcn_mfma_f32_16x16x32_bf16(ag, qf[1][kk], sa1, 0, 0, 0);
        }
        // p = exp(cos/tau); lane holds (q-row = l15, key = quad*4+r) -> already
        // the 16x16x16 A-frag layout. Accumulate denominator partials.
        U16x4 pk0, pk1;
#pragma unroll
        for (int r = 0; r < 4; ++r) {
            float p0 = exp2f(sa0[r] * 3.6067376022224085f);
            float p1 = exp2f(sa1[r] * 3.6067376022224085f);
            dl0 += p0; dl1 += p1;
            pk0.us[r] = f2bf(p0);
            pk1.us[r] = f2bf(p1);
        }
        __syncthreads();                    // barrier A: sGmc readers done, dmaB drained
        if (mt < 31) dmaA((mt + 1) * 64);   // covered by GEMM2, drained at barrier B

        // GEMM2 key-split: O_partial[32 rows][256 c] += P[32][16 keys] * V[16][256]
#pragma unroll
        for (int ct = 0; ct < 16; ++ct) {
            short4v bb = *(const short4v*)&gBbase[ct * 1024];
            o[0][ct] = mfma16x16(pk0.s4, bb, o[0][ct]);
            o[1][ct] = mfma16x16(pk1.s4, bb, o[1][ct]);
        }
        __syncthreads();                    // barrier B: sGcm readers done, dmaA drained
        if (mt < 31) dmaB((mt + 1) * 64);   // covered by next GEMM1, drained at barrier A
    }

    // ---- denominators: quad-reduce, publish per key-quarter per row ----
    {
        float d0 = dl0;
        d0 += __shfl_xor(d0, 16);
        d0 += __shfl_xor(d0, 32);
        float d1 = dl1;
        d1 += __shfl_xor(d1, 16);
        d1 += __shfl_xor(d1, 32);
        if (quad == 0) {
            sDen[kh][rh * 32 + l15] = d0;
            sDen[kh][rh * 32 + 16 + l15] = d1;
        }
    }

    // ---- O reduction: 4 static rounds (rh x rt) through 64 KB LDS dump ----
    // slot(kh', j, quad, l15) = kh'*1024 + j*64 + quad*16 + l15  (f32x4 units)
    // Writes/reads are 1 KB contiguous per j -> conflict-free. All indices static.
    f32x4* red4 = (f32x4*)sMem;
    const int wslot = kh * 1024 + quad * 16 + l15;       // + j*64
    const int rslot = (4 * kh) * 64 + quad * 16 + l15;   // + jj*64 + kh'*1024
    f32x4 oacc0[4], oacc1[4];

#define RED_ROUND(RH, OSRC, ODST)                                              \
    __syncthreads();                                                           \
    if (rh == (RH)) {                                                          \
        _Pragma("unroll")                                                      \
        for (int j = 0; j < 16; ++j) red4[wslot + j * 64] = OSRC[j];           \
    }                                                                          \
    __syncthreads();                                                           \
    if (rh == (RH)) {                                                          \
        _Pragma("unroll")                                                      \
        for (int jj = 0; jj < 4; ++jj) {                                       \
            const int base = rslot + jj * 64;                                  \
            ODST[jj] = red4[base] + red4[base + 1024] +                        \
                       red4[base + 2048] + red4[base + 3072];                  \
        }                                                                      \
    }

    RED_ROUND(0, o[0], oacc0)
    RED_ROUND(0, o[1], oacc1)
    RED_ROUND(1, o[0], oacc0)
    RED_ROUND(1, o[1], oacc1)
#undef RED_ROUND

    // ---- epilogue: wave (kh, rh) owns rows [32rh,32rh+32), c [64kh, 64kh+64) ----
    const float* lb = l + ((size_t)b * N_ + row0 + rh * 32) * C_;
    float* ob = out + ((size_t)b * N_ + row0 + rh * 32) * C_;
#pragma unroll
    for (int r = 0; r < 4; ++r) {
        {   // row-tile 0
            const int row = quad * 4 + r;
            const int grow = rh * 32 + row;
            const float inv = 1.f / (sDen[0][grow] + sDen[1][grow] + sDen[2][grow] + sDen[3][grow]);
            const size_t rb = (size_t)row * C_;
#pragma unroll
            for (int jj = 0; jj < 4; ++jj) {
                const int c = kh * 64 + jj * 16 + l15;
                ob[rb + c] = lb[rb + c] + oacc0[jj][r] * inv;
            }
        }
        {   // row-tile 1
            const int row = 16 + quad * 4 + r;
            const int grow = rh * 32 + row;
            const float inv = 1.f / (sDen[0][grow] + sDen[1][grow] + sDen[2][grow] + sDen[3][grow]);
            const size_t rb = (size_t)row * C_;
#pragma unroll
            for (int jj = 0; jj < 4; ++jj) {
                const int c = kh * 64 + jj * 16 + l15;
                ob[rb + c] = lb[rb + c] + oacc1[jj][r] * inv;
            }
        }
    }
}

extern "C" void kernel_launch(void* const* d_in, const int* in_sizes, int n_in,
                              void* d_out, int out_size, void* d_ws, size_t ws_size,
                              hipStream_t stream) {
    (void)in_sizes; (void)n_in; (void)out_size; (void)ws_size;
    const float* l = (const float*)d_in[0];
    const float* g = (const float*)d_in[1];
    float* outp = (float*)d_out;

    char* ws = (char*)d_ws;
    unsigned short* gmc = (unsigned short*)ws;                                   // 4 MB (normalized, [b][m][c])
    unsigned short* gcm = (unsigned short*)(ws + (size_t)B_ * M_ * C_ * 2);      // 4 MB (raw, [b][c][m])

    k_prep<<<dim3(M_ / 64, B_), 256, 0, stream>>>(g, gcm, gmc);
    k_main<<<dim3(N_ / 64 * B_), 512, 0, stream>>>(l, gcm, gmc, outp);
}

// Round 7
// 136.857 us; speedup vs baseline: 5.0984x; 1.0210x over previous
//
#include <hip/hip_runtime.h>

#define B_ 4
#define N_ 4096
#define C_ 256
#define M_ 2048

typedef __attribute__((ext_vector_type(8))) short short8;
typedef __attribute__((ext_vector_type(4))) short short4v;
typedef __attribute__((ext_vector_type(4))) float f32x4;

union U16x8 { uint4 u4; unsigned short us[8]; short8 s8; };
union U16x4 { uint2 u2; unsigned short us[4]; short4v s4; };

__device__ __forceinline__ float bf2f(unsigned short h) {
    unsigned int u = ((unsigned int)h) << 16;
    return __builtin_bit_cast(float, u);
}
__device__ __forceinline__ unsigned short f2bf(float f) {
    unsigned int u = __builtin_bit_cast(unsigned int, f);
    u += 0x7FFFu + ((u >> 16) & 1u);
    return (unsigned short)(u >> 16);
}

#define GLB_AS(p) ((const __attribute__((address_space(1))) unsigned int*)(p))
#define LDS_AS(p) ((__attribute__((address_space(3))) unsigned int*)(p))

// 16x16x16 bf16 MFMA: builtin if available, else raw encoding via inline asm.
__device__ __forceinline__ f32x4 mfma16x16(short4v a, short4v b, f32x4 c) {
#if __has_builtin(__builtin_amdgcn_mfma_f32_16x16x16bf16_1k)
    return __builtin_amdgcn_mfma_f32_16x16x16bf16_1k(a, b, c, 0, 0, 0);
#else
    asm("v_mfma_f32_16x16x16_bf16 %0, %1, %2, %0" : "+v"(c) : "v"(a), "v"(b));
    return c;
#endif
}

// ---- Fused prepass (WIDE): norms + casts. grid (M/64, B), 1024 thr ----
// v12's k_prep was latency-bound: 128 blocks x 256 thr (half the CUs idle),
// 64-deep serial strided-load chain in phase 1, 9 barriered sub-phases.
// Same math, same tiles, 4x the threads: phase-1 chain 64->16 loads/thread,
// phase-2 one float4-chunk per thread per c-tile.
__global__ __launch_bounds__(1024) void k_prep(const float* __restrict__ g,
                                               unsigned short* __restrict__ gcm,
                                               unsigned short* __restrict__ gmc) {
    __shared__ float red[16][64];
    __shared__ float sInv[64];
    __shared__ unsigned short T[64 * 66];   // normalized [c][m] tile, odd-dword stride
    const int b = blockIdx.y, m0 = blockIdx.x * 64;
    const int tid = threadIdx.x;                // 0..1023
    const int ml = tid & 63, cq = tid >> 6;     // cq in [0,16)

    // phase 1: norms — each thread sums 16 c-rows (was 64)
    const float* gb = g + (size_t)b * C_ * M_ + m0 + ml;
    float ss = 0.f;
#pragma unroll 4
    for (int i = 0; i < 16; ++i) {
        float v = gb[(size_t)(cq * 16 + i) * M_];
        ss += v * v;
    }
    red[cq][ml] = ss;
    __syncthreads();
    if (cq == 0) {
        float t = 0.f;
#pragma unroll
        for (int k = 0; k < 16; ++k) t += red[k][ml];
        sInv[ml] = 1.f / fmaxf(sqrtf(t), 1e-8f);
    }
    __syncthreads();

    // phase 2: casts, 4 c-tiles of 64
    for (int c0 = 0; c0 < C_; c0 += 64) {
        const float* gbase = g + ((size_t)b * C_ + c0) * M_ + m0;
        unsigned short* gcmb = gcm + ((size_t)b * C_ + c0) * M_ + m0;
        {
            int id = tid;                       // 1024 float4-chunks, 1 per thread
            int ci = id >> 4, mq = (id & 15) * 4;
            float4 v = *(const float4*)(gbase + (size_t)ci * M_ + mq);
            uint2 pk;
            pk.x = (unsigned)f2bf(v.x) | ((unsigned)f2bf(v.y) << 16);
            pk.y = (unsigned)f2bf(v.z) | ((unsigned)f2bf(v.w) << 16);
            *(uint2*)(gcmb + (size_t)ci * M_ + mq) = pk;
            T[ci * 66 + mq + 0] = f2bf(v.x * sInv[mq + 0]);
            T[ci * 66 + mq + 1] = f2bf(v.y * sInv[mq + 1]);
            T[ci * 66 + mq + 2] = f2bf(v.z * sInv[mq + 2]);
            T[ci * 66 + mq + 3] = f2bf(v.w * sInv[mq + 3]);
        }
        __syncthreads();
        unsigned short* gmcb = gmc + ((size_t)b * M_ + m0) * C_ + c0;
        if (tid < 512) {                        // 512 8-short chunks
            int mr = tid >> 3, cc8 = (tid & 7) * 8;
            U16x8 t;
#pragma unroll
            for (int k = 0; k < 8; ++k) t.us[k] = T[(cc8 + k) * 66 + mr];
            *(uint4*)(gmcb + (size_t)mr * C_ + cc8) = t.u4;
        }
        __syncthreads();   // T reused next tile
    }
}

// ---------------- Main fused kernel (v13 == v10, byte-exact) ----------------
// 64 query rows / block, 8 waves (512 thr), 256 blocks = 1/CU (zero tail).
// Wave (kh = w&3, rh = w>>2): keys [16kh,16kh+16), rows [32rh, 32rh+32).
// Single-buffered tiles, two __syncthreads per iter (PROVEN correct at
// absmax 0.03125 / 70.5 us). The double-buffered variants (v11/v12) failed
// deterministically (identical absmax under two different sync schemes) --
// reverted; do not re-attempt without disasm evidence.
__global__ __launch_bounds__(512, 2) void k_main(
    const float* __restrict__ l,
    const unsigned short* __restrict__ gcm,    // [B][C][M] raw bf16   (GEMM2 B, k=m contig)
    const unsigned short* __restrict__ gmc,    // [B][M][C] normalized (GEMM1 A, k=c contig)
    float* __restrict__ out)
{
    __shared__ __align__(16) char sMem[66560];
    unsigned short* sGmc = (unsigned short*)sMem;              // ghat [m][c], 32 KB
    unsigned short* sGcm = (unsigned short*)(sMem + 32768);    // graw [c][m], 32 KB
    float (*sDen)[64] = (float (*)[64])(sMem + 65536);         // [4 kh][64 rows]

    const int tid = threadIdx.x;
    const int w = tid >> 6;
    const int lane = tid & 63;
    const int l15 = lane & 15;
    const int quad = lane >> 4;
    const int kh = w & 3;        // key-quarter
    const int rh = w >> 2;       // row-half

    // ---- batch-clustered XCD swizzle (bijective over 256 blocks) ----
    const int bid = blockIdx.x;
    const int xcd = bid & 7;
    const int b = xcd >> 1;                                   // 2 XCDs per batch
    const int row0 = (((bid >> 3) << 1) | (xcd & 1)) * 64;    // 64-row tile in [0,4096)

    // per-lane DMA source offsets (shorts), XOR chunk swizzles match the read patterns
    int goffA[4], goffB[4];
#pragma unroll
    for (int i = 0; i < 4; ++i) {
        int p = (w * 4 + i) * 64 + lane;                   // p in [0,2048)
        int rA = p >> 5;                                   // row in [0,64), 32 granules/row
        goffA[i] = rA * 256 + (((p & 31) ^ (rA & 31)) << 3);
        int rB = p >> 3;                                   // row in [0,256), 8 granules/row
        goffB[i] = rB * 2048 + (((p & 7) ^ ((rB >> 1) & 7)) << 3);
    }

    const unsigned short* gmc_b = gmc + (size_t)b * M_ * C_;
    const unsigned short* gcm_b = gcm + (size_t)b * C_ * M_;

    auto dmaA = [&](int m0) {
#pragma unroll
        for (int i = 0; i < 4; ++i)
            __builtin_amdgcn_global_load_lds(GLB_AS(gmc_b + (size_t)m0 * 256 + goffA[i]),
                                             LDS_AS(&sGmc[(w * 4 + i) * 512]), 16, 0, 0);
    };
    auto dmaB = [&](int m0) {
#pragma unroll
        for (int i = 0; i < 4; ++i)
            __builtin_amdgcn_global_load_lds(GLB_AS(gcm_b + (size_t)m0 + goffB[i]),
                                             LDS_AS(&sGcm[(w * 4 + i) * 512]), 16, 0, 0);
    };

    dmaA(0);
    dmaB(0);

    // ---- Q: my 32 rows (row-half rh), row norm, normalize -> bf16 B-frags ----
    short8 qf[2][8];
#pragma unroll
    for (int rt = 0; rt < 2; ++rt) {
        const float* lrow = l + ((size_t)b * N_ + row0 + rh * 32 + rt * 16 + l15) * C_;
        U16x8 qt[8];
        float ss = 0.f;
#pragma unroll
        for (int kk = 0; kk < 8; ++kk) {
            float4 x0 = *(const float4*)(lrow + kk * 32 + quad * 8);
            float4 x1 = *(const float4*)(lrow + kk * 32 + quad * 8 + 4);
            ss += x0.x*x0.x + x0.y*x0.y + x0.z*x0.z + x0.w*x0.w;
            ss += x1.x*x1.x + x1.y*x1.y + x1.z*x1.z + x1.w*x1.w;
            qt[kk].us[0] = f2bf(x0.x); qt[kk].us[1] = f2bf(x0.y);
            qt[kk].us[2] = f2bf(x0.z); qt[kk].us[3] = f2bf(x0.w);
            qt[kk].us[4] = f2bf(x1.x); qt[kk].us[5] = f2bf(x1.y);
            qt[kk].us[6] = f2bf(x1.z); qt[kk].us[7] = f2bf(x1.w);
        }
        ss += __shfl_xor(ss, 16);
        ss += __shfl_xor(ss, 32);
        const float invl = 1.0f / fmaxf(sqrtf(ss), 1e-8f);
#pragma unroll
        for (int kk = 0; kk < 8; ++kk) {
            U16x8 t;
#pragma unroll
            for (int j = 0; j < 8; ++j) t.us[j] = f2bf(bf2f(qt[kk].us[j]) * invl);
            qf[rt][kk] = t.s8;
        }
    }

    __syncthreads();   // drains DMA(tile 0)

    f32x4 zero = {0.f, 0.f, 0.f, 0.f};
    f32x4 o[2][16];    // per-wave PARTIAL O (its 16 keys): [row-tile][c-tile 16c]
#pragma unroll
    for (int i = 0; i < 2; ++i)
#pragma unroll
        for (int j = 0; j < 16; ++j) o[i][j] = zero;
    float dl0 = 0.f, dl1 = 0.f;

    // GEMM1 A-frag source: my 16 key-rows of sGmc
    const unsigned short* gAbase = &sGmc[(kh * 16 + l15) * 256];
    const int rxor = (kh * 16 + l15) & 31;
    // GEMM2 B-frag source: chunk-of-4 XOR swizzle (matches goffB granule swizzle)
    const int chunkXor = (kh * 4 + quad) ^ (l15 & 14);
    const unsigned short* gBbase = &sGcm[l15 * 64 + (chunkXor << 2)];

    for (int mt = 0; mt < 32; ++mt) {
        // GEMM1 (swapped): S^T[16 keys][16 rows] per row-tile, K=256
        f32x4 sa0 = zero, sa1 = zero;
#pragma unroll
        for (int kk = 0; kk < 8; ++kk) {
            short8 ag = *(const short8*)&gAbase[((kk * 4 + quad) ^ rxor) << 3];
            sa0 = __builtin_amdgcn_mfma_f32_16x16x32_bf16(ag, qf[0][kk], sa0, 0, 0, 0);
            sa1 = __builtin_amdgcn_mfma_f32_16x16x32_bf16(ag, qf[1][kk], sa1, 0, 0, 0);
        }
        // p = exp(cos/tau); lane holds (q-row = l15, key = quad*4+r) -> already
        // the 16x16x16 A-frag layout. Accumulate denominator partials.
        U16x4 pk0, pk1;
#pragma unroll
        for (int r = 0; r < 4; ++r) {
            float p0 = exp2f(sa0[r] * 3.6067376022224085f);
            float p1 = exp2f(sa1[r] * 3.6067376022224085f);
            dl0 += p0; dl1 += p1;
            pk0.us[r] = f2bf(p0);
            pk1.us[r] = f2bf(p1);
        }
        __syncthreads();                    // barrier A: sGmc readers done, dmaB drained
        if (mt < 31) dmaA((mt + 1) * 64);   // covered by GEMM2, drained at barrier B

        // GEMM2 key-split: O_partial[32 rows][256 c] += P[32][16 keys] * V[16][256]
#pragma unroll
        for (int ct = 0; ct < 16; ++ct) {
            short4v bb = *(const short4v*)&gBbase[ct * 1024];
            o[0][ct] = mfma16x16(pk0.s4, bb, o[0][ct]);
            o[1][ct] = mfma16x16(pk1.s4, bb, o[1][ct]);
        }
        __syncthreads();                    // barrier B: sGcm readers done, dmaA drained
        if (mt < 31) dmaB((mt + 1) * 64);   // covered by next GEMM1, drained at barrier A
    }

    // ---- denominators: quad-reduce, publish per key-quarter per row ----
    {
        float d0 = dl0;
        d0 += __shfl_xor(d0, 16);
        d0 += __shfl_xor(d0, 32);
        float d1 = dl1;
        d1 += __shfl_xor(d1, 16);
        d1 += __shfl_xor(d1, 32);
        if (quad == 0) {
            sDen[kh][rh * 32 + l15] = d0;
            sDen[kh][rh * 32 + 16 + l15] = d1;
        }
    }

    // ---- O reduction: 4 static rounds (rh x rt) through 64 KB LDS dump ----
    // slot(kh', j, quad, l15) = kh'*1024 + j*64 + quad*16 + l15  (f32x4 units)
    // Writes/reads are 1 KB contiguous per j -> conflict-free. All indices static.
    f32x4* red4 = (f32x4*)sMem;
    const int wslot = kh * 1024 + quad * 16 + l15;       // + j*64
    const int rslot = (4 * kh) * 64 + quad * 16 + l15;   // + jj*64 + kh'*1024
    f32x4 oacc0[4], oacc1[4];

#define RED_ROUND(RH, OSRC, ODST)                                              \
    __syncthreads();                                                           \
    if (rh == (RH)) {                                                          \
        _Pragma("unroll")                                                      \
        for (int j = 0; j < 16; ++j) red4[wslot + j * 64] = OSRC[j];           \
    }                                                                          \
    __syncthreads();                                                           \
    if (rh == (RH)) {                                                          \
        _Pragma("unroll")                                                      \
        for (int jj = 0; jj < 4; ++jj) {                                       \
            const int base = rslot + jj * 64;                                  \
            ODST[jj] = red4[base] + red4[base + 1024] +                        \
                       red4[base + 2048] + red4[base + 3072];                  \
        }                                                                      \
    }

    RED_ROUND(0, o[0], oacc0)
    RED_ROUND(0, o[1], oacc1)
    RED_ROUND(1, o[0], oacc0)
    RED_ROUND(1, o[1], oacc1)
#undef RED_ROUND

    // ---- epilogue: wave (kh, rh) owns rows [32rh,32rh+32), c [64kh, 64kh+64) ----
    const float* lb = l + ((size_t)b * N_ + row0 + rh * 32) * C_;
    float* ob = out + ((size_t)b * N_ + row0 + rh * 32) * C_;
#pragma unroll
    for (int r = 0; r < 4; ++r) {
        {   // row-tile 0
            const int row = quad * 4 + r;
            const int grow = rh * 32 + row;
            const float inv = 1.f / (sDen[0][grow] + sDen[1][grow] + sDen[2][grow] + sDen[3][grow]);
            const size_t rb = (size_t)row * C_;
#pragma unroll
            for (int jj = 0; jj < 4; ++jj) {
                const int c = kh * 64 + jj * 16 + l15;
                ob[rb + c] = lb[rb + c] + oacc0[jj][r] * inv;
            }
        }
        {   // row-tile 1
            const int row = 16 + quad * 4 + r;
            const int grow = rh * 32 + row;
            const float inv = 1.f / (sDen[0][grow] + sDen[1][grow] + sDen[2][grow] + sDen[3][grow]);
            const size_t rb = (size_t)row * C_;
#pragma unroll
            for (int jj = 0; jj < 4; ++jj) {
                const int c = kh * 64 + jj * 16 + l15;
                ob[rb + c] = lb[rb + c] + oacc1[jj][r] * inv;
            }
        }
    }
}

extern "C" void kernel_launch(void* const* d_in, const int* in_sizes, int n_in,
                              void* d_out, int out_size, void* d_ws, size_t ws_size,
                              hipStream_t stream) {
    (void)in_sizes; (void)n_in; (void)out_size; (void)ws_size;
    const float* l = (const float*)d_in[0];
    const float* g = (const float*)d_in[1];
    float* outp = (float*)d_out;

    char* ws = (char*)d_ws;
    unsigned short* gmc = (unsigned short*)ws;                                   // 4 MB (normalized, [b][m][c])
    unsigned short* gcm = (unsigned short*)(ws + (size_t)B_ * M_ * C_ * 2);      // 4 MB (raw, [b][c][m])

    k_prep<<<dim3(M_ / 64, B_), 1024, 0, stream>>>(g, gcm, gmc);
    k_main<<<dim3(N_ / 64 * B_), 512, 0, stream>>>(l, gcm, gmc, outp);
}